// Round 8
// baseline (94.951 us; speedup 1.0000x reference)
//
#include <hip/hip_runtime.h>
#include <math.h>

// ---------------- output offsets (floats) ----------------
#define O_Q     0
#define O_LOSS  2097152
#define O_IDX   2097153
#define O_PERP  2129921
#define O_NECS  2129922
#define O_EMAW  2130946
#define O_W     2196482

// ---------------- workspace offsets (4-byte units) ----------------
#define W_WT     0          // 65536  transposed weight [64][1024] fp32
#define W_SW2    65536      // 1024   (float, rounded from fp64)
#define W_IDX    66560      // 32768  (int)
#define W_CNT    99328      // 1024   counts
#define W_DW     100352     // 65536  dw
#define W_LOSS   165888     // 1      loss accum
#define W_CS     165952     // 1024   cluster_size
#define W_ZN     66561      // floats to zero starting at W_CNT (cnt+dw+loss)

// =====================================================================
// kernel 0: transpose weight -> wT[64][1024]; wsq[c] = fl32(fp64 sum w^2);
// also zero counts/dw/loss region (replaces hipMemsetAsync dispatch).
// =====================================================================
__global__ __launch_bounds__(256)
void k_prep(const float* __restrict__ w, float* __restrict__ wT,
            float* __restrict__ wsq, float* __restrict__ zbase) {
    __shared__ float sh[64][65];
    int tid = threadIdx.x;
    int j0 = blockIdx.x * 64;
    for (int z = blockIdx.x * 256 + tid; z < W_ZN; z += 16 * 256) zbase[z] = 0.f;

    for (int p = 0; p < 16; ++p) {
        int f = p * 256 + tid;
        int j = f >> 6, d = f & 63;
        sh[j][d] = w[(j0 + j) * 64 + d];
    }
    __syncthreads();
    for (int p = 0; p < 16; ++p) {
        int f = p * 256 + tid;
        int d = f >> 6, jj = f & 63;
        wT[d * 1024 + j0 + jj] = sh[jj][d];
    }
    if (tid < 64) {
        double s = 0.0;
        #pragma unroll
        for (int d = 0; d < 64; ++d) {
            double v = (double)sh[tid][d];
            s = fma(v, v, s);
        }
        wsq[j0 + tid] = (float)s;
    }
}

// =====================================================================
// kernel 1: fp32 scores + argmin — barrier-free k-loop, L2-streamed w.
// grid 1024 x block 256 (4 ty-groups x 64 tx lanes); 32 rows/block,
// 8 rows x 8 codes per thread; 2 code-chunks of 512. w-fragments are
// read directly from global wT (L2-resident, coalesced 1KB/wave); only
// the x tile (8KB) + rsq live in LDS -> 4 blocks/CU, 16 waves/CU.
// Numerics bitwise-identical to round-4 PASSING kernel:
//   score = fl32( fl32(rsq[r]+wsq[c]) - 2*dot ), dot = seq fp32 FMA k=0..63,
//   rsq/wsq = fl32(fp64 sums), ties -> lowest code index.
// =====================================================================
__global__ __launch_bounds__(256, 4)
void k_dist(const float* __restrict__ x, const float* __restrict__ wT,
            const float* __restrict__ wsq,
            int* __restrict__ idx_int, float* __restrict__ out_idxf) {
    __shared__ float xs[64][32];    // [k][row] 8 KB
    __shared__ float rsq[32];
    int tid = threadIdx.x;
    int tx = tid & 63, ty = tid >> 6;   // tx: lane/codes, ty: row group (wave-uniform)
    int r0 = ty * 8;
    int rbase = blockIdx.x * 32;
    int b = rbase >> 10, hw0 = rbase & 1023;
    const float* xb = x + b * 65536 + hw0;

    // stage x tile: xs[d][r]
    #pragma unroll
    for (int p = 0; p < 2; ++p) {
        int f = p * 256 + tid;
        int d = f >> 3, r4 = (f & 7) << 2;
        *(float4*)&xs[d][r4] = *(const float4*)(xb + d * 1024 + r4);
    }
    __syncthreads();
    if (tid < 32) {                      // fp64 row norms, k ascending
        double s = 0.0;
        #pragma unroll
        for (int d = 0; d < 64; ++d) {
            double v = (double)xs[d][tid];
            s = fma(v, v, s);
        }
        rsq[tid] = (float)s;
    }
    __syncthreads();

    float rq[8];
    #pragma unroll
    for (int i = 0; i < 8; ++i) rq[i] = rsq[r0 + i];

    float best[8];
    int   bidx[8];
    #pragma unroll
    for (int i = 0; i < 8; ++i) { best[i] = 3.4e38f; bidx[i] = 0; }

    #pragma unroll 1
    for (int ch = 0; ch < 2; ++ch) {
        int cb = ch * 512;
        const float4* wp0 = (const float4*)(wT + cb + tx * 4);        // +k*1024
        const float4* wp1 = (const float4*)(wT + cb + 256 + tx * 4);

        float acc[8][8];
        #pragma unroll
        for (int i = 0; i < 8; ++i)
            #pragma unroll
            for (int j = 0; j < 8; ++j) acc[i][j] = 0.f;

        #pragma unroll 2
        for (int k = 0; k < 64; ++k) {
            float4 wb0 = wp0[k * 256];     // global, L2-hot, coalesced
            float4 wb1 = wp1[k * 256];
            // broadcast x reads (wave-uniform address)
            float4 xa0 = *(float4*)&xs[k][r0];
            float4 xa1 = *(float4*)&xs[k][r0 + 4];
            float xr[8] = {xa0.x, xa0.y, xa0.z, xa0.w,
                           xa1.x, xa1.y, xa1.z, xa1.w};
            float wc[8] = {wb0.x, wb0.y, wb0.z, wb0.w,
                           wb1.x, wb1.y, wb1.z, wb1.w};
            #pragma unroll
            for (int i = 0; i < 8; ++i)
                #pragma unroll
                for (int j = 0; j < 8; ++j)
                    acc[i][j] += xr[i] * wc[j];
        }

        // scoring; (ch, cp, j) ascending per thread => strict < keeps first min
        float4 wsa = *(const float4*)(wsq + cb + tx * 4);
        float4 wsb = *(const float4*)(wsq + cb + 256 + tx * 4);
        float s2v[8] = {wsa.x, wsa.y, wsa.z, wsa.w,
                        wsb.x, wsb.y, wsb.z, wsb.w};
        #pragma unroll
        for (int cp = 0; cp < 2; ++cp)
            #pragma unroll
            for (int j = 0; j < 4; ++j) {
                int jj = cp * 4 + j;
                int c = cb + cp * 256 + tx * 4 + j;
                float s2 = s2v[jj];
                #pragma unroll
                for (int i = 0; i < 8; ++i) {
                    float t1 = rq[i] + s2;              // fl32 add @ ~64
                    float sc = t1 - 2.0f * acc[i][jj];  // 2*dot exact; one rounding
                    if (sc < best[i]) { best[i] = sc; bidx[i] = c; }
                }
            }
    }

    // argmin reduce across 64 lanes (codes on lanes; tie -> lower index)
    #pragma unroll
    for (int off = 1; off < 64; off <<= 1) {
        #pragma unroll
        for (int i = 0; i < 8; ++i) {
            float ov = __shfl_xor(best[i], off);
            int   oi = __shfl_xor(bidx[i], off);
            if (ov < best[i] || (ov == best[i] && oi < bidx[i])) {
                best[i] = ov; bidx[i] = oi;
            }
        }
    }
    if (tx == 0) {
        #pragma unroll
        for (int i = 0; i < 8; ++i) {
            int r = rbase + r0 + i;
            idx_int[r]  = bidx[i];
            out_idxf[r] = (float)bidx[i];
        }
    }
}

// =====================================================================
// kernel 2: quantized output + loss + counts + dw (block = 64 vectors)
// xs stride 65 -> dw column reads are 2-way (free); round-4-verified.
// =====================================================================
__global__ __launch_bounds__(256)
void k_quant(const float* __restrict__ x, const float* __restrict__ w,
             const int* __restrict__ idx_int, float* __restrict__ outq,
             float* __restrict__ counts, float* __restrict__ dw,
             float* __restrict__ loss) {
    __shared__ float xs[64][65];
    __shared__ int   idxl[64];
    __shared__ float red[4];
    int tid = threadIdx.x;
    int n0  = blockIdx.x * 64;
    int b   = n0 >> 10, hw0 = n0 & 1023;
    const float* xb = x + b * 65536 + hw0;

    if (tid < 64) {
        int id = idx_int[n0 + tid];
        idxl[tid] = id;
        atomicAdd(&counts[id], 1.0f);
    }
    for (int p = 0; p < 16; ++p) {
        int f = p * 256 + tid;
        int d = f >> 6, n = f & 63;
        xs[d][n] = xb[d * 1024 + n];
    }
    __syncthreads();

    float ll = 0.f;
    for (int p = 0; p < 16; ++p) {
        int f = p * 256 + tid;
        int d = f >> 6, n = f & 63;
        float q  = w[idxl[n] * 64 + d];
        float xv = xs[d][n];
        float dd = q - xv;
        ll += dd * dd;
        outq[b * 65536 + d * 1024 + hw0 + n] = q;
    }
    #pragma unroll
    for (int off = 32; off; off >>= 1) ll += __shfl_down(ll, off);
    if ((tid & 63) == 0) red[tid >> 6] = ll;
    __syncthreads();
    if (tid == 0) atomicAdd(loss, red[0] + red[1] + red[2] + red[3]);

    // dw: lane = d, one coalesced 256B atomic row per vector
    int wv = tid >> 6, lane = tid & 63;
    for (int v = 0; v < 16; ++v) {
        int n = wv * 16 + v;
        atomicAdd(&dw[idxl[n] * 64 + lane], xs[lane][n]);
    }
}

// =====================================================================
// kernel 3a: scalars + cluster_size (single block, 1024 threads)
// =====================================================================
__global__ __launch_bounds__(1024)
void k_final_a(const float* __restrict__ ema_cs, const float* __restrict__ counts,
               const float* __restrict__ loss, float* __restrict__ cs_ws,
               float* __restrict__ out) {
    __shared__ float redA[16], redB[16];
    __shared__ float ntot_sh;
    int tid = threadIdx.x;

    float c    = counts[tid];
    float necs = 0.99f * ema_cs[tid] + 0.01f * c;
    out[O_NECS + tid] = necs;

    float p   = c * (1.0f / 32768.0f);
    float ent = -p * logf(p + 1e-10f);

    float s1 = necs, s2 = ent;
    #pragma unroll
    for (int off = 32; off; off >>= 1) {
        s1 += __shfl_down(s1, off);
        s2 += __shfl_down(s2, off);
    }
    int wv = tid >> 6;
    if ((tid & 63) == 0) { redA[wv] = s1; redB[wv] = s2; }
    __syncthreads();
    if (tid == 0) {
        float t1 = 0.f, t2 = 0.f;
        for (int i = 0; i < 16; ++i) { t1 += redA[i]; t2 += redB[i]; }
        ntot_sh = t1;
        out[O_PERP] = expf(t2);
        out[O_LOSS] = 0.25f * loss[0] * (1.0f / 2097152.0f);
    }
    __syncthreads();
    float ntot = ntot_sh;
    cs_ws[tid] = (necs + 1e-5f) / (ntot + 1024.0f * 1e-5f) * ntot;
}

// =====================================================================
// kernel 3b: EMA-w + new weight (256 blocks x 256 threads)
// =====================================================================
__global__ __launch_bounds__(256)
void k_final_b(const float* __restrict__ ema_w, const float* __restrict__ dw,
               const float* __restrict__ cs_ws, float* __restrict__ out) {
    int f = blockIdx.x * 256 + threadIdx.x;
    int j = f >> 6;
    float ne = 0.99f * ema_w[f] + 0.01f * dw[f];
    out[O_EMAW + f] = ne;
    out[O_W + f]    = ne / cs_ws[j];
}

// =====================================================================
extern "C" void kernel_launch(void* const* d_in, const int* in_sizes, int n_in,
                              void* d_out, int out_size, void* d_ws, size_t ws_size,
                              hipStream_t stream) {
    const float* x      = (const float*)d_in[0];
    const float* w      = (const float*)d_in[1];
    const float* ema_cs = (const float*)d_in[2];
    const float* ema_w  = (const float*)d_in[3];
    float* out = (float*)d_out;
    float* ws  = (float*)d_ws;

    float* wT     = ws + W_WT;
    float* wsq    = ws + W_SW2;
    int*   idxi   = (int*)(ws + W_IDX);
    float* counts = ws + W_CNT;
    float* dwb    = ws + W_DW;
    float* lossb  = ws + W_LOSS;
    float* cs_ws  = ws + W_CS;

    k_prep   <<<16,   256, 0, stream>>>(w, wT, wsq, counts);
    k_dist   <<<1024, 256, 0, stream>>>(x, wT, wsq, idxi, out + O_IDX);
    k_quant  <<<512,  256, 0, stream>>>(x, w, idxi, out + O_Q, counts, dwb, lossb);
    k_final_a<<<1,   1024, 0, stream>>>(ema_cs, counts, lossb, cs_ws, out);
    k_final_b<<<256,  256, 0, stream>>>(ema_w, dwb, cs_ws, out);
}